// Round 7
// baseline (279.633 us; speedup 1.0000x reference)
//
#include <hip/hip_runtime.h>
#include <math.h>

// ---------------------------------------------------------------------------
// DeformableFeatureAggregation — MI355X
// Pipeline (7 launches):
//   k_stage      : FUSED: feat L0..L3 (6,256,H,W) fp32 -> featF (6,H,W,256)
//                  fp8 via barrier-free direct transpose. This round: ALL 32
//                  strided loads issued into an explicit register array with
//                  sched_barrier(0) fence (r6: VGPR=28 showed compiler
//                  serialized loads -> 2.46 TB/s latency-bound; forcing
//                  32-deep pipeline needs ~50 VGPR).
//                  iw->Ab (fragment-swizzled bf16); [W_wts|W_learn]->Bb
//                  (fragment-swizzled, column-permuted to task order);
//                  W_out->Wob; b_wts->biasP.
//   k_wts_mfma   : MFMA -> logitsP bf16 (4096x2496, task-ordered) + learn.
//   k_sample x4  : SPLIT 4x1024 (attribution probe: visibility threshold
//                  ~21us; the ~130us invisible band must surface next round).
//   k_out_mfma   : MFMA out = featsB @ W_out^T + b_out + iw (fp32)
// Fragment-swizzled layout (halves): tile16 t = row/16, ml = row&15;
//   off(row,k) = t*4096 + (k/32)*512 + ((k%32)/8)*128 + ml*8 + (k%8)
// Workspace (float offsets):
//   featF  : bytes 0..22978560                (f 0..5744640)
//   logitsP: f 5744640   (4096x2496 ush)  -> 10856448
//   featsB : f 10856448  (4096x256 ush)   -> 11380736
//   learn  : f 11380736  (4096x18 f)      -> 11454464
//   Ab     : f 11454464  (4096x256 ush)   -> 11978752
//   Bb     : f 11978752  (2560x256 ush)   -> 12306432
//   Wob    : f 12306432  (256x256 ush)    -> 12339200
//   biasP  : f 12339200  (2496 f)         -> 12341696   (~49.4 MB)
// ---------------------------------------------------------------------------

#define FT_L0 0
#define FT_L1 17301504
#define FT_L2 21626880
#define FT_L3 22708224
#define WS_LOGB 5744640
#define WS_FEATB 10856448
#define WS_LEARN 11380736
#define WS_AB 11454464
#define WS_BB 11978752
#define WS_WOB 12306432
#define WS_BIASP 12339200

typedef float v2f __attribute__((ext_vector_type(2)));
typedef __attribute__((ext_vector_type(8))) short bf16x8;
typedef __attribute__((ext_vector_type(4))) float f32x4;

__device__ const float FIXS[7][3] = {
    {0.f, 0.f, 0.f},  {0.45f, 0.f, 0.f}, {-0.45f, 0.f, 0.f}, {0.f, 0.45f, 0.f},
    {0.f, -0.45f, 0.f}, {0.f, 0.f, 0.45f}, {0.f, 0.f, -0.45f}};

__device__ __forceinline__ unsigned int f2bf(float f) {
  unsigned int u = __float_as_uint(f);
  u += 0x7fffu + ((u >> 16) & 1u);  // RTNE
  return u >> 16;
}
__device__ __forceinline__ float bf2f(unsigned short u) {
  return __uint_as_float(((unsigned int)u) << 16);
}

// FUSED staging kernel. grid 6347 = 4608 (transpose: 12 xt x 64 y x 6 cam) +
// 1024 (Ab) + 640 (Bb) + 64 (Wob) + 11 (biasP).
__global__ __launch_bounds__(256) void k_stage(
    const float* __restrict__ f0, const float* __restrict__ f1,
    const float* __restrict__ f2, const float* __restrict__ f3,
    unsigned char* __restrict__ featF,
    const float* __restrict__ iw, const float* __restrict__ Ww,
    const float* __restrict__ Wl, const float* __restrict__ Wo,
    const float* __restrict__ b_wts,
    unsigned short* __restrict__ Ab, unsigned short* __restrict__ Bb,
    unsigned short* __restrict__ Wob, float* __restrict__ biasP) {
  __shared__ unsigned short smu[32][33];
  const int tid = threadIdx.x;
  const int bid = blockIdx.x;
  if (bid < 4608) {
    // ---- transpose: (6,256,H,W) fp32 -> (6,H,W,256) fp8, barrier-free ----
    // thread = (x = tid&31 within 32-x tile, q8 = tid>>5 -> 32-channel group)
    const int bx = bid % 12;
    const int y = (bid / 12) & 63;
    const int c = bid / 768;  // cam 0..5
    const float* src;
    unsigned char* dst;
    int H, W, xt;
    if (bx < 6)       { src = f0; dst = featF + FT_L0; H = 64; W = 176; xt = bx * 32; }
    else if (bx < 9)  { src = f1; dst = featF + FT_L1; H = 32; W = 88;  xt = (bx - 6) * 32; }
    else if (bx < 11) { src = f2; dst = featF + FT_L2; H = 16; W = 44;  xt = (bx - 9) * 32; }
    else              { src = f3; dst = featF + FT_L3; H = 8;  W = 22;  xt = 0; }
    if (y >= H) return;
    const int x = xt + (tid & 31);
    if (x >= W) return;
    const int q8 = tid >> 5;  // 0..7 -> channels q8*32 .. q8*32+31
    const int HW = H * W;
    const float* sp = src + ((c * 256 + q8 * 32) * H + y) * W + x;
    // issue ALL 32 strided loads before any conversion (32-deep pipeline);
    // sched_barrier(0) stops the scheduler from sinking loads past cvt use.
    float v[32];
#pragma unroll
    for (int k = 0; k < 32; ++k) v[k] = sp[k * HW];
    __builtin_amdgcn_sched_barrier(0);
    unsigned int r[8];
#pragma unroll
    for (int k8 = 0; k8 < 8; ++k8) {
      int pk = __builtin_amdgcn_cvt_pk_fp8_f32(v[k8 * 4 + 0], v[k8 * 4 + 1], 0, false);
      pk = __builtin_amdgcn_cvt_pk_fp8_f32(v[k8 * 4 + 2], v[k8 * 4 + 3], pk, true);
      r[k8] = (unsigned int)pk;
    }
    unsigned char* drow = dst + (((c * H + y) * W + x) * 256) + q8 * 32;
    *(uint4*)(drow)      = make_uint4(r[0], r[1], r[2], r[3]);
    *(uint4*)(drow + 16) = make_uint4(r[4], r[5], r[6], r[7]);
    return;
  }
  const int bx = bid - 4608;  // 0..1738
  if (bx < 1024) {
    // ---- Ab: iw -> fragment-swizzled bf16 ----
    const int i = bx * 256 + tid;
    const float4 v = ((const float4*)iw)[i];
    uint2 o;
    o.x = f2bf(v.x) | (f2bf(v.y) << 16);
    o.y = f2bf(v.z) | (f2bf(v.w) << 16);
    const int mtile = i >> 10;
    const int ml = (i >> 6) & 15;
    const int kk = (i & 63) >> 3;
    const int q = (i >> 1) & 3;
    const int jj = (i & 1) * 4;
    *(uint2*)&Ab[mtile * 4096 + kk * 512 + q * 128 + ml * 8 + jj] = o;
    return;
  }
  const int i = tid & 31;
  const int r = tid >> 5;
  const int bxb = bx - 1024;  // 0..714
  if (bxb < 640) {
    // ---- Bb: [W_wts|W_learn] -> fragment-swizzled, column-permuted ----
    const int j0 = (bxb % 80) * 32;   // source col tile
    const int k0 = (bxb / 80) * 32;   // k tile
#pragma unroll
    for (int rr = r; rr < 32; rr += 8) {
      const int k = k0 + rr, jc = j0 + i;
      float v = 0.f;
      if (jc < 2496) v = Ww[k * 2496 + jc];
      else if (jc < 2514) v = Wl[k * 18 + (jc - 2496)];
      smu[rr][i] = (unsigned short)f2bf(v);  // tile[k_in][j_in]
    }
    __syncthreads();
    const int jn = tid >> 3;   // 0..31 col within tile
    const int kq = tid & 7;    // 0..7  k-quad within tile
    const int jc = j0 + jn;
    if (jc < 2514) {
      int colp;
      if (jc < 2496) {
        const int g = jc & 7, s = jc >> 3;
        const int c = s / 52, r2 = s - c * 52;
        const int l = r2 / 13, p = r2 - l * 13;
        colp = g * 312 + (p * 6 + c) * 4 + l;
      } else {
        colp = jc;  // learn cols 2496..2513 stay in place
      }
      const int k = k0 + kq * 4;
      const int ntile = colp >> 4, mln = colp & 15;
      const int kkn = k >> 5, qn = (k >> 3) & 3, jj = k & 7;
      unsigned int h0 = (unsigned int)smu[kq * 4 + 0][jn] |
                        ((unsigned int)smu[kq * 4 + 1][jn] << 16);
      unsigned int h1 = (unsigned int)smu[kq * 4 + 2][jn] |
                        ((unsigned int)smu[kq * 4 + 3][jn] << 16);
      *(uint2*)&Bb[ntile * 4096 + kkn * 512 + qn * 128 + mln * 8 + jj] =
          make_uint2(h0, h1);
    }
    return;
  }
  const int bxw = bxb - 640;  // 0..74
  if (bxw < 64) {
    // ---- Wob: W_out transpose -> row-major bf16 ----
    const int j0 = (bxw & 7) * 32;
    const int k0 = (bxw >> 3) * 32;
#pragma unroll
    for (int rr = r; rr < 32; rr += 8)
      smu[rr][i] = (unsigned short)f2bf(Wo[(k0 + rr) * 256 + j0 + i]);
    __syncthreads();
#pragma unroll
    for (int rr = r; rr < 32; rr += 8)
      Wob[(j0 + rr) * 256 + k0 + i] = smu[i][rr];
    return;
  }
  // ---- biasP: permute b_wts into task order ----
  {
    const int jcol = (bxw - 64) * 256 + tid;
    if (jcol < 2496) {
      const int g = jcol & 7, s = jcol >> 3;
      const int c = s / 52, r2 = s - c * 52;
      const int l = r2 / 13, p = r2 - l * 13;
      biasP[g * 312 + (p * 6 + c) * 4 + l] = b_wts[jcol];
    }
  }
}

// MFMA GEMM: [logitsP | learn] = A(4096x256) @ B^T + bias. grid (40,64).
// bx<39: task-ordered logits tile, LDS-staged 128B-coalesced stores.
// bx=39: learn columns (sigmoid, scalar path).
__global__ __launch_bounds__(256) void k_wts_mfma(
    const unsigned short* __restrict__ Ab, const unsigned short* __restrict__ Bb,
    const float* __restrict__ biasP, const float* __restrict__ b_learn,
    unsigned short* __restrict__ logitsP, float* __restrict__ learn) {
  __shared__ __align__(16) unsigned short t64[64][88];
  const int tid = threadIdx.x;
  const int w = tid >> 6, lane = tid & 63;
  const int ml = lane & 15, q = lane >> 4;
  const int n0 = blockIdx.x * 64;
  const int m0 = blockIdx.y * 64;
  f32x4 acc[4] = {{0.f, 0.f, 0.f, 0.f}, {0.f, 0.f, 0.f, 0.f},
                  {0.f, 0.f, 0.f, 0.f}, {0.f, 0.f, 0.f, 0.f}};
  const unsigned short* Ap = Ab + (blockIdx.y * 4 + w) * 4096 + lane * 8;
  const unsigned short* Bp = Bb + blockIdx.x * 4 * 4096 + lane * 8;
#pragma unroll
  for (int kk = 0; kk < 8; ++kk) {
    const bf16x8 a = *(const bf16x8*)(Ap + kk * 512);
#pragma unroll
    for (int nt = 0; nt < 4; ++nt) {
      const bf16x8 b = *(const bf16x8*)(Bp + nt * 4096 + kk * 512);
      acc[nt] = __builtin_amdgcn_mfma_f32_16x16x32_bf16(a, b, acc[nt], 0, 0, 0);
    }
  }
  if (blockIdx.x < 39) {
    const int wr = w * 16 + q * 4;
#pragma unroll
    for (int nt = 0; nt < 4; ++nt) {
      const float b = biasP[n0 + nt * 16 + ml];
#pragma unroll
      for (int r = 0; r < 4; ++r)
        t64[wr + r][nt * 16 + ml] = (unsigned short)f2bf(acc[nt][r] + b);
    }
    __syncthreads();
    const int row = tid >> 2, cq = tid & 3;
    unsigned short* drow = logitsP + (m0 + row) * 2496 + n0;
    *(uint4*)(drow + cq * 8) = *(const uint4*)&t64[row][cq * 8];
    *(uint4*)(drow + 32 + cq * 8) = *(const uint4*)&t64[row][32 + cq * 8];
  } else {
    const int rowb = m0 + w * 16 + q * 4;
#pragma unroll
    for (int nt = 0; nt < 4; ++nt) {
      const int col = n0 + nt * 16 + ml;
      if (col < 2514) {
        const float b = b_learn[col - 2496];
#pragma unroll
        for (int r = 0; r < 4; ++r) {
          float v = fminf(fmaxf(acc[nt][r] + b, -9.21f), 9.21f);
          learn[(rowb + r) * 18 + (col - 2496)] = 1.f / (1.f + expf(-v)) - 0.5f;
        }
      }
    }
  }
}

// 16 fp8 channels of one corner, weighted-accumulate into 8 packed f32 pairs.
__device__ __forceinline__ void fma16(const uint4 u, const float s, v2f* acc) {
  const v2f w = {s, s};
  acc[0] += __builtin_amdgcn_cvt_pk_f32_fp8((int)u.x, false) * w;
  acc[1] += __builtin_amdgcn_cvt_pk_f32_fp8((int)u.x, true) * w;
  acc[2] += __builtin_amdgcn_cvt_pk_f32_fp8((int)u.y, false) * w;
  acc[3] += __builtin_amdgcn_cvt_pk_f32_fp8((int)u.y, true) * w;
  acc[4] += __builtin_amdgcn_cvt_pk_f32_fp8((int)u.z, false) * w;
  acc[5] += __builtin_amdgcn_cvt_pk_f32_fp8((int)u.z, true) * w;
  acc[6] += __builtin_amdgcn_cvt_pk_f32_fp8((int)u.w, false) * w;
  acc[7] += __builtin_amdgcn_cvt_pk_f32_fp8((int)u.w, true) * w;
}

// Fused per-anchor sampler. grid 1024 x 256, launched 4x (nbase 0..3072).
__global__ __launch_bounds__(256, 8) void k_sample(
    const float* __restrict__ anchor, const unsigned short* __restrict__ logitsP,
    const float* __restrict__ learn_g, const unsigned char* __restrict__ featF,
    const float* __restrict__ proj, const float* __restrict__ wh,
    unsigned short* __restrict__ featsB, const int nbase) {
  const int n = nbase + blockIdx.x;
  const int tid = threadIdx.x;
  const int lane = tid & 63;
  const int wave = tid >> 6;
  __shared__ __align__(16) unsigned short s_w[8 * 328];  // bf16 weights [g][t]
  __shared__ float s_p2d[78][2];
  __shared__ float s_learn[18];
  __shared__ union SmpLds {
    struct { int4 off[320]; float4 wt[320]; } tab;  // 10240 B
    float red[4][256];                              //  4096 B
  } u;

  // phase 1: pre-permuted logits row -> LDS (pure linear uint4 copy).
  {
    const uint4* lp = (const uint4*)(logitsP + (size_t)n * 2496);
    for (int i = tid; i < 312; i += 256) {
      const int g = i / 39;
      ((uint4*)s_w)[g * 41 + (i - g * 39)] = lp[i];
    }
  }
  if (tid < 64) s_w[(tid >> 3) * 328 + 312 + (tid & 7)] = 0;  // zero pad tasks
  if (tid < 18) s_learn[tid] = learn_g[n * 18 + tid];
  __syncthreads();

  // phase 2: softmax over the 312 tasks per group; wave w -> groups 2w, 2w+1
#pragma unroll
  for (int gg = 0; gg < 2; ++gg) {
    unsigned short* row = &s_w[(wave * 2 + gg) * 328];
    float l[5];
    float mx = -1e30f;
#pragma unroll
    for (int i = 0; i < 5; ++i) {
      const int s = lane + i * 64;
      l[i] = (s < 312) ? bf2f(row[s]) : -1e30f;
      mx = fmaxf(mx, l[i]);
    }
    for (int off = 32; off; off >>= 1) mx = fmaxf(mx, __shfl_xor(mx, off));
    float sum = 0.f;
#pragma unroll
    for (int i = 0; i < 5; ++i) {
      l[i] = __expf(l[i] - mx);
      sum += l[i];
    }
    for (int off = 32; off; off >>= 1) sum += __shfl_xor(sum, off);
    const float inv = 1.f / sum;
#pragma unroll
    for (int i = 0; i < 5; ++i) {
      const int s = lane + i * 64;
      if (s < 312) row[s] = (unsigned short)f2bf(l[i] * inv);
    }
  }

  // phase 3: projection of 78 (pt,cam) pairs
  if (tid < 78) {
    const int p = tid / 6, c = tid % 6;
    const float* an = anchor + n * 11;
    float qw = an[6], qx = an[7], qy = an[8], qz = an[9];
    const float qinv = 1.f / sqrtf(qw * qw + qx * qx + qy * qy + qz * qz);
    qw *= qinv; qx *= qinv; qy *= qinv; qz *= qinv;
    const float R00 = 1.f - 2.f * (qy * qy + qz * qz), R01 = 2.f * (qx * qy - qw * qz), R02 = 2.f * (qx * qz + qw * qy);
    const float R10 = 2.f * (qx * qy + qw * qz), R11 = 1.f - 2.f * (qx * qx + qz * qz), R12 = 2.f * (qy * qz - qw * qx);
    const float R20 = 2.f * (qx * qz - qw * qy), R21 = 2.f * (qy * qz + qw * qx), R22 = 1.f - 2.f * (qx * qx + qy * qy);
    float s0, s1, s2;
    if (p < 7) {
      s0 = FIXS[p][0]; s1 = FIXS[p][1]; s2 = FIXS[p][2];
    } else {
      const int b = (p - 7) * 3;
      s0 = s_learn[b]; s1 = s_learn[b + 1]; s2 = s_learn[b + 2];
    }
    const float vx = s0 * an[3], vy = s1 * an[4], vz = s2 * an[5];
    const float kx = R00 * vx + R10 * vy + R20 * vz + an[0];
    const float ky = R01 * vx + R11 * vy + R21 * vz + an[1];
    const float kz = R02 * vx + R12 * vy + R22 * vz + an[2];
    const float* P = proj + c * 16;
    const float h0 = P[0] * kx + P[1] * ky + P[2] * kz + P[3];
    const float h1 = P[4] * kx + P[5] * ky + P[6] * kz + P[7];
    const float h2 = P[8] * kx + P[9] * ky + P[10] * kz + P[11];
    const float zz = fmaxf(h2, 1e-5f);
    float px = h0 / zz / wh[c * 2 + 0];
    float py = h1 / zz / wh[c * 2 + 1];
    px = fminf(fmaxf(px, 0.f), 0.9999f);
    py = fminf(fmaxf(py, 0.f), 0.9999f);
    s_p2d[tid][0] = px;
    s_p2d[tid][1] = py;
  }
  __syncthreads();

  // phase 4: per-task corner BYTE offsets + bilinear weights; pad tasks zeroed
  {
    constexpr int LBB[4] = {FT_L0, FT_L1, FT_L2, FT_L3};
    constexpr int CSB[4] = {2883584, 720896, 180224, 45056};  // H*W*256
    for (int t = tid; t < 320; t += 256) {
      const int pc = t >> 2, l = t & 3;
      if (pc >= 78) {
        u.tab.off[t] = make_int4(0, 0, 0, 0);
        u.tab.wt[t] = make_float4(0.f, 0.f, 0.f, 0.f);
        continue;
      }
      const int c = pc % 6;
      const int H = 64 >> l, W = 176 >> l;
      const float fx = s_p2d[pc][0] * (float)W - 0.5f;
      const float fy = s_p2d[pc][1] * (float)H - 0.5f;
      const float x0f = floorf(fx), y0f = floorf(fy);
      const float wx = fx - x0f, wy = fy - y0f;
      const int x0 = (int)x0f, y0 = (int)y0f;
      const float mx0 = (x0 >= 0) ? 1.f : 0.f;
      const float mx1 = (x0 + 1 < W) ? 1.f : 0.f;
      const float my0 = (y0 >= 0) ? 1.f : 0.f;
      const float my1 = (y0 + 1 < H) ? 1.f : 0.f;
      const int cx0 = max(x0, 0), cx1 = min(x0 + 1, W - 1);
      const int cy0 = max(y0, 0), cy1 = min(y0 + 1, H - 1);
      const int base = LBB[l] + c * CSB[l];
      int4 o;
      o.x = base + (cy0 * W + cx0) * 256;
      o.y = base + (cy0 * W + cx1) * 256;
      o.z = base + (cy1 * W + cx0) * 256;
      o.w = base + (cy1 * W + cx1) * 256;
      u.tab.off[t] = o;
      float4 w4;
      w4.x = (1.f - wx) * (1.f - wy) * mx0 * my0;
      w4.y = wx * (1.f - wy) * mx1 * my0;
      w4.z = (1.f - wx) * wy * mx0 * my1;
      w4.w = wx * wy * mx1 * my1;
      u.tab.wt[t] = w4;
    }
  }
  __syncthreads();

  // phase 5: fp8 gather. quarter-wave = one pc; 16 fp8 channels per lane.
  const int q = lane >> 4;
  const int ql = lane & 15;
  const int chb = ql * 16;
  const int g = ql >> 1;
  v2f acc[8];
#pragma unroll
  for (int k = 0; k < 8; ++k) acc[k] = (v2f){0.f, 0.f};
  const unsigned char* fbl = featF + chb;  // per-lane pre-offset base
  const unsigned short* wrow = &s_w[g * 328];
  const int pcb = wave * 4 + q;
#pragma unroll
  for (int it = 0; it < 5; ++it) {
    const int pc = pcb + it * 16;   // < 80 (tasks >= 312 are zero-weighted)
    const int t0 = pc * 4;
    const uint2 wq = *(const uint2*)&wrow[t0];  // 4 bf16 level-weights
    float wgl[4];
    wgl[0] = __uint_as_float(wq.x << 16);
    wgl[1] = __uint_as_float(wq.x & 0xffff0000u);
    wgl[2] = __uint_as_float(wq.y << 16);
    wgl[3] = __uint_as_float(wq.y & 0xffff0000u);
#pragma unroll
    for (int l4 = 0; l4 < 4; ++l4) {
      const int t = t0 + l4;
      const int4 o = u.tab.off[t];
      const float4 bw = u.tab.wt[t];
      const float wg = wgl[l4];
      const uint4 u0 = *(const uint4*)(fbl + o.x);
      const uint4 u1 = *(const uint4*)(fbl + o.y);
      const uint4 u2 = *(const uint4*)(fbl + o.z);
      const uint4 u3 = *(const uint4*)(fbl + o.w);
      fma16(u0, bw.x * wg, acc);
      fma16(u1, bw.y * wg, acc);
      fma16(u2, bw.z * wg, acc);
      fma16(u3, bw.w * wg, acc);
    }
  }
#pragma unroll
  for (int k = 0; k < 8; ++k) {
    v2f b;
    b.x = __shfl_xor(acc[k].x, 16);
    b.y = __shfl_xor(acc[k].y, 16);
    acc[k] += b;
    b.x = __shfl_xor(acc[k].x, 32);
    b.y = __shfl_xor(acc[k].y, 32);
    acc[k] += b;
  }
  __syncthreads();  // u.tab reads done in ALL waves before u.red is written
  if (lane < 16) {
    float* dst = &u.red[wave][ql * 16];
    *(float4*)(dst + 0)  = make_float4(acc[0].x, acc[0].y, acc[1].x, acc[1].y);
    *(float4*)(dst + 4)  = make_float4(acc[2].x, acc[2].y, acc[3].x, acc[3].y);
    *(float4*)(dst + 8)  = make_float4(acc[4].x, acc[4].y, acc[5].x, acc[5].y);
    *(float4*)(dst + 12) = make_float4(acc[6].x, acc[6].y, acc[7].x, acc[7].y);
  }
  __syncthreads();
  {
    const float sum = u.red[0][tid] + u.red[1][tid] + u.red[2][tid] + u.red[3][tid];
    featsB[n * 256 + tid] = (unsigned short)f2bf(sum);
  }
}

// MFMA GEMM: out = featsB(4096x256) @ Wob^T + b_out + resid. grid (4,64)
__global__ __launch_bounds__(256) void k_out_mfma(
    const unsigned short* __restrict__ Ab, const unsigned short* __restrict__ Bb,
    const float* __restrict__ bias, const float* __restrict__ resid,
    float* __restrict__ out) {
  const int tid = threadIdx.x;
  const int w = tid >> 6, lane = tid & 63;
  const int ml = lane & 15, q = lane >> 4;
  const int n0 = blockIdx.x * 64;
  const int m0 = blockIdx.y * 64;
  f32x4 acc[4] = {{0.f, 0.f, 0.f, 0.f}, {0.f, 0.f, 0.f, 0.f},
                  {0.f, 0.f, 0.f, 0.f}, {0.f, 0.f, 0.f, 0.f}};
  const unsigned short* Ap = Ab + (m0 + w * 16 + ml) * 256 + q * 8;
  const unsigned short* Bp = Bb + (n0 + ml) * 256 + q * 8;
#pragma unroll
  for (int kk = 0; kk < 8; ++kk) {
    const bf16x8 a = *(const bf16x8*)(Ap + kk * 32);
#pragma unroll
    for (int nt = 0; nt < 4; ++nt) {
      const bf16x8 b = *(const bf16x8*)(Bp + nt * 16 * 256 + kk * 32);
      acc[nt] = __builtin_amdgcn_mfma_f32_16x16x32_bf16(a, b, acc[nt], 0, 0, 0);
    }
  }
  const int rowb = m0 + w * 16 + q * 4;
#pragma unroll
  for (int nt = 0; nt < 4; ++nt) {
    const int col = n0 + nt * 16 + ml;
    const float b = bias[col];
#pragma unroll
    for (int r = 0; r < 4; ++r) {
      const int row = rowb + r;
      out[row * 256 + col] = acc[nt][r] + b + resid[row * 256 + col];
    }
  }
}

extern "C" void kernel_launch(void* const* d_in, const int* in_sizes, int n_in,
                              void* d_out, int out_size, void* d_ws, size_t ws_size,
                              hipStream_t stream) {
  (void)in_sizes; (void)n_in; (void)out_size; (void)ws_size;
  const float* iw      = (const float*)d_in[1];
  const float* anchor  = (const float*)d_in[2];
  const float* f0      = (const float*)d_in[3];
  const float* f1      = (const float*)d_in[4];
  const float* f2      = (const float*)d_in[5];
  const float* f3      = (const float*)d_in[6];
  const float* proj    = (const float*)d_in[7];
  const float* wh      = (const float*)d_in[8];
  const float* W_learn = (const float*)d_in[9];
  const float* b_learn = (const float*)d_in[10];
  const float* W_wts   = (const float*)d_in[11];
  const float* b_wts   = (const float*)d_in[12];
  const float* W_out   = (const float*)d_in[13];
  const float* b_out   = (const float*)d_in[14];
  float* out = (float*)d_out;
  float* ws = (float*)d_ws;
  unsigned char*  featF   = (unsigned char*)ws;
  unsigned short* logitsP = (unsigned short*)(ws + WS_LOGB);
  unsigned short* featsB  = (unsigned short*)(ws + WS_FEATB);
  float*          learn   = ws + WS_LEARN;
  unsigned short* Ab      = (unsigned short*)(ws + WS_AB);
  unsigned short* Bb      = (unsigned short*)(ws + WS_BB);
  unsigned short* Wob     = (unsigned short*)(ws + WS_WOB);
  float*          biasP   = ws + WS_BIASP;

  k_stage<<<6347, 256, 0, stream>>>(f0, f1, f2, f3, featF, iw, W_wts, W_learn,
                                    W_out, b_wts, Ab, Bb, Wob, biasP);
  k_wts_mfma<<<dim3(40, 64), 256, 0, stream>>>(Ab, Bb, biasP, b_learn, logitsP, learn);
  k_sample<<<1024, 256, 0, stream>>>(anchor, logitsP, learn, featF, proj, wh, featsB, 0);
  k_sample<<<1024, 256, 0, stream>>>(anchor, logitsP, learn, featF, proj, wh, featsB, 1024);
  k_sample<<<1024, 256, 0, stream>>>(anchor, logitsP, learn, featF, proj, wh, featsB, 2048);
  k_sample<<<1024, 256, 0, stream>>>(anchor, logitsP, learn, featF, proj, wh, featsB, 3072);
  k_out_mfma<<<dim3(4, 64), 256, 0, stream>>>(featsB, Wob, b_out, iw, out);
}

// Round 9
// 246.029 us; speedup vs baseline: 1.1366x; 1.1366x over previous
//
#include <hip/hip_runtime.h>
#include <math.h>

// ---------------------------------------------------------------------------
// DeformableFeatureAggregation — MI355X
// Pipeline (4 launches). Cooperative single-kernel variant FAILED on this
// harness (r8: container error — hipLaunchCooperativeKernel incompatible with
// the bench's graph capture). Multi-launch it is; boundaries cost ~10us each
// (r6->r7 A/B), so launch count is minimized instead.
//   k_stage    : FUSED: feat L0..L3 (6,256,H,W) fp32 -> featF (6,H,W,256) fp8
//                via barrier-free direct transpose, FLOAT2 x-vectorized:
//                thread owns 2 x-positions x 32 ch = 32x8B strided loads
//                (r6/r7: compiler caps ILP at ~6-7 loads; doubling bytes/load
//                doubles in-flight bytes -> target ~2x of 2.46 TB/s).
//                iw->Ab (fragment-swizzled bf16); [W_wts|W_learn]->Bb
//                (fragment-swizzled, column-permuted to task order);
//                W_out->Wob; b_wts->biasP.
//   k_wts_mfma : MFMA -> logitsP bf16 (4096x2496, task-ordered) + learn.
//   k_sample   : single 4096-block launch (r6 2-way split was an attribution
//                probe; merged to save one boundary).
//   k_out_mfma : MFMA out = featsB @ W_out^T + b_out + iw (fp32)
// Fragment-swizzled layout (halves): tile16 t = row/16, ml = row&15;
//   off(row,k) = t*4096 + (k/32)*512 + ((k%32)/8)*128 + ml*8 + (k%8)
// Workspace (float offsets): featF 0; logitsP 5744640; featsB 10856448;
//   learn 11380736; Ab 11454464; Bb 11978752; Wob 12306432; biasP 12339200
// ---------------------------------------------------------------------------

#define FT_L0 0
#define FT_L1 17301504
#define FT_L2 21626880
#define FT_L3 22708224
#define WS_LOGB 5744640
#define WS_FEATB 10856448
#define WS_LEARN 11380736
#define WS_AB 11454464
#define WS_BB 11978752
#define WS_WOB 12306432
#define WS_BIASP 12339200

typedef float v2f __attribute__((ext_vector_type(2)));
typedef __attribute__((ext_vector_type(8))) short bf16x8;
typedef __attribute__((ext_vector_type(4))) float f32x4;

__device__ const float FIXS[7][3] = {
    {0.f, 0.f, 0.f},  {0.45f, 0.f, 0.f}, {-0.45f, 0.f, 0.f}, {0.f, 0.45f, 0.f},
    {0.f, -0.45f, 0.f}, {0.f, 0.f, 0.45f}, {0.f, 0.f, -0.45f}};

__device__ __forceinline__ unsigned int f2bf(float f) {
  unsigned int u = __float_as_uint(f);
  u += 0x7fffu + ((u >> 16) & 1u);  // RTNE
  return u >> 16;
}
__device__ __forceinline__ float bf2f(unsigned short u) {
  return __uint_as_float(((unsigned int)u) << 16);
}

// FUSED staging kernel. grid 4427 = 2688 (transpose: 7 xt64 x 64 y x 6 cam) +
// 1024 (Ab) + 640 (Bb) + 64 (Wob) + 11 (biasP).
__global__ __launch_bounds__(256) void k_stage(
    const float* __restrict__ f0, const float* __restrict__ f1,
    const float* __restrict__ f2, const float* __restrict__ f3,
    unsigned char* __restrict__ featF,
    const float* __restrict__ iw, const float* __restrict__ Ww,
    const float* __restrict__ Wl, const float* __restrict__ Wo,
    const float* __restrict__ b_wts,
    unsigned short* __restrict__ Ab, unsigned short* __restrict__ Bb,
    unsigned short* __restrict__ Wob, float* __restrict__ biasP) {
  __shared__ unsigned short smu[32][33];
  const int tid = threadIdx.x;
  const int bid = blockIdx.x;
  if (bid < 2688) {
    // ---- transpose: (6,256,H,W) fp32 -> (6,H,W,256) fp8, float2/x-pair ----
    const int bx7 = bid % 7;
    const int y = (bid / 7) & 63;
    const int c = bid / 448;  // cam 0..5
    const float* src;
    unsigned char* dst;
    int H, W, xt;
    if (bx7 < 3)      { src = f0; dst = featF + FT_L0; H = 64; W = 176; xt = bx7 * 64; }
    else if (bx7 < 5) { src = f1; dst = featF + FT_L1; H = 32; W = 88;  xt = (bx7 - 3) * 64; }
    else if (bx7 < 6) { src = f2; dst = featF + FT_L2; H = 16; W = 44;  xt = 0; }
    else              { src = f3; dst = featF + FT_L3; H = 8;  W = 22;  xt = 0; }
    if (y >= H) return;
    const int x = xt + (tid & 31) * 2;  // W even, x even -> x+1 safe when x<W
    if (x >= W) return;
    const int q8 = tid >> 5;  // 0..7 -> channels q8*32 .. q8*32+31
    const int HW = H * W;
    const float* sp = src + ((c * 256 + q8 * 32) * H + y) * W + x;
    float2 v[32];
#pragma unroll
    for (int k = 0; k < 32; ++k) v[k] = *(const float2*)(sp + k * HW);
    __builtin_amdgcn_sched_barrier(0);
    unsigned int r0[8], r1[8];
#pragma unroll
    for (int k8 = 0; k8 < 8; ++k8) {
      int pk = __builtin_amdgcn_cvt_pk_fp8_f32(v[k8 * 4 + 0].x, v[k8 * 4 + 1].x, 0, false);
      pk = __builtin_amdgcn_cvt_pk_fp8_f32(v[k8 * 4 + 2].x, v[k8 * 4 + 3].x, pk, true);
      r0[k8] = (unsigned int)pk;
      int pk1 = __builtin_amdgcn_cvt_pk_fp8_f32(v[k8 * 4 + 0].y, v[k8 * 4 + 1].y, 0, false);
      pk1 = __builtin_amdgcn_cvt_pk_fp8_f32(v[k8 * 4 + 2].y, v[k8 * 4 + 3].y, pk1, true);
      r1[k8] = (unsigned int)pk1;
    }
    unsigned char* drow = dst + (((c * H + y) * W + x) * 256) + q8 * 32;
    *(uint4*)(drow)            = make_uint4(r0[0], r0[1], r0[2], r0[3]);
    *(uint4*)(drow + 16)       = make_uint4(r0[4], r0[5], r0[6], r0[7]);
    *(uint4*)(drow + 256)      = make_uint4(r1[0], r1[1], r1[2], r1[3]);
    *(uint4*)(drow + 256 + 16) = make_uint4(r1[4], r1[5], r1[6], r1[7]);
    return;
  }
  const int bx = bid - 2688;  // 0..1738
  if (bx < 1024) {
    // ---- Ab: iw -> fragment-swizzled bf16 ----
    const int i = bx * 256 + tid;
    const float4 v = ((const float4*)iw)[i];
    uint2 o;
    o.x = f2bf(v.x) | (f2bf(v.y) << 16);
    o.y = f2bf(v.z) | (f2bf(v.w) << 16);
    const int mtile = i >> 10;
    const int ml = (i >> 6) & 15;
    const int kk = (i & 63) >> 3;
    const int q = (i >> 1) & 3;
    const int jj = (i & 1) * 4;
    *(uint2*)&Ab[mtile * 4096 + kk * 512 + q * 128 + ml * 8 + jj] = o;
    return;
  }
  const int i = tid & 31;
  const int r = tid >> 5;
  const int bxb = bx - 1024;  // 0..714
  if (bxb < 640) {
    // ---- Bb: [W_wts|W_learn] -> fragment-swizzled, column-permuted ----
    const int j0 = (bxb % 80) * 32;   // source col tile
    const int k0 = (bxb / 80) * 32;   // k tile
#pragma unroll
    for (int rr = r; rr < 32; rr += 8) {
      const int k = k0 + rr, jc = j0 + i;
      float v = 0.f;
      if (jc < 2496) v = Ww[k * 2496 + jc];
      else if (jc < 2514) v = Wl[k * 18 + (jc - 2496)];
      smu[rr][i] = (unsigned short)f2bf(v);  // tile[k_in][j_in]
    }
    __syncthreads();
    const int jn = tid >> 3;   // 0..31 col within tile
    const int kq = tid & 7;    // 0..7  k-quad within tile
    const int jc = j0 + jn;
    if (jc < 2514) {
      int colp;
      if (jc < 2496) {
        const int g = jc & 7, s = jc >> 3;
        const int c = s / 52, r2 = s - c * 52;
        const int l = r2 / 13, p = r2 - l * 13;
        colp = g * 312 + (p * 6 + c) * 4 + l;
      } else {
        colp = jc;  // learn cols 2496..2513 stay in place
      }
      const int k = k0 + kq * 4;
      const int ntile = colp >> 4, mln = colp & 15;
      const int kkn = k >> 5, qn = (k >> 3) & 3, jj = k & 7;
      unsigned int h0 = (unsigned int)smu[kq * 4 + 0][jn] |
                        ((unsigned int)smu[kq * 4 + 1][jn] << 16);
      unsigned int h1 = (unsigned int)smu[kq * 4 + 2][jn] |
                        ((unsigned int)smu[kq * 4 + 3][jn] << 16);
      *(uint2*)&Bb[ntile * 4096 + kkn * 512 + qn * 128 + mln * 8 + jj] =
          make_uint2(h0, h1);
    }
    return;
  }
  const int bxw = bxb - 640;  // 0..74
  if (bxw < 64) {
    // ---- Wob: W_out transpose -> row-major bf16 ----
    const int j0 = (bxw & 7) * 32;
    const int k0 = (bxw >> 3) * 32;
#pragma unroll
    for (int rr = r; rr < 32; rr += 8)
      smu[rr][i] = (unsigned short)f2bf(Wo[(k0 + rr) * 256 + j0 + i]);
    __syncthreads();
#pragma unroll
    for (int rr = r; rr < 32; rr += 8)
      Wob[(j0 + rr) * 256 + k0 + i] = smu[i][rr];
    return;
  }
  // ---- biasP: permute b_wts into task order ----
  {
    const int jcol = (bxw - 64) * 256 + tid;
    if (jcol < 2496) {
      const int g = jcol & 7, s = jcol >> 3;
      const int c = s / 52, r2 = s - c * 52;
      const int l = r2 / 13, p = r2 - l * 13;
      biasP[g * 312 + (p * 6 + c) * 4 + l] = b_wts[jcol];
    }
  }
}

// MFMA GEMM: [logitsP | learn] = A(4096x256) @ B^T + bias. grid (40,64).
// bx<39: task-ordered logits tile, LDS-staged 128B-coalesced stores.
// bx=39: learn columns (sigmoid, scalar path).
__global__ __launch_bounds__(256) void k_wts_mfma(
    const unsigned short* __restrict__ Ab, const unsigned short* __restrict__ Bb,
    const float* __restrict__ biasP, const float* __restrict__ b_learn,
    unsigned short* __restrict__ logitsP, float* __restrict__ learn) {
  __shared__ __align__(16) unsigned short t64[64][88];
  const int tid = threadIdx.x;
  const int w = tid >> 6, lane = tid & 63;
  const int ml = lane & 15, q = lane >> 4;
  const int n0 = blockIdx.x * 64;
  const int m0 = blockIdx.y * 64;
  f32x4 acc[4] = {{0.f, 0.f, 0.f, 0.f}, {0.f, 0.f, 0.f, 0.f},
                  {0.f, 0.f, 0.f, 0.f}, {0.f, 0.f, 0.f, 0.f}};
  const unsigned short* Ap = Ab + (blockIdx.y * 4 + w) * 4096 + lane * 8;
  const unsigned short* Bp = Bb + blockIdx.x * 4 * 4096 + lane * 8;
#pragma unroll
  for (int kk = 0; kk < 8; ++kk) {
    const bf16x8 a = *(const bf16x8*)(Ap + kk * 512);
#pragma unroll
    for (int nt = 0; nt < 4; ++nt) {
      const bf16x8 b = *(const bf16x8*)(Bp + nt * 4096 + kk * 512);
      acc[nt] = __builtin_amdgcn_mfma_f32_16x16x32_bf16(a, b, acc[nt], 0, 0, 0);
    }
  }
  if (blockIdx.x < 39) {
    const int wr = w * 16 + q * 4;
#pragma unroll
    for (int nt = 0; nt < 4; ++nt) {
      const float b = biasP[n0 + nt * 16 + ml];
#pragma unroll
      for (int r = 0; r < 4; ++r)
        t64[wr + r][nt * 16 + ml] = (unsigned short)f2bf(acc[nt][r] + b);
    }
    __syncthreads();
    const int row = tid >> 2, cq = tid & 3;
    unsigned short* drow = logitsP + (m0 + row) * 2496 + n0;
    *(uint4*)(drow + cq * 8) = *(const uint4*)&t64[row][cq * 8];
    *(uint4*)(drow + 32 + cq * 8) = *(const uint4*)&t64[row][32 + cq * 8];
  } else {
    const int rowb = m0 + w * 16 + q * 4;
#pragma unroll
    for (int nt = 0; nt < 4; ++nt) {
      const int col = n0 + nt * 16 + ml;
      if (col < 2514) {
        const float b = b_learn[col - 2496];
#pragma unroll
        for (int r = 0; r < 4; ++r) {
          float v = fminf(fmaxf(acc[nt][r] + b, -9.21f), 9.21f);
          learn[(rowb + r) * 18 + (col - 2496)] = 1.f / (1.f + expf(-v)) - 0.5f;
        }
      }
    }
  }
}

// 16 fp8 channels of one corner, weighted-accumulate into 8 packed f32 pairs.
__device__ __forceinline__ void fma16(const uint4 u, const float s, v2f* acc) {
  const v2f w = {s, s};
  acc[0] += __builtin_amdgcn_cvt_pk_f32_fp8((int)u.x, false) * w;
  acc[1] += __builtin_amdgcn_cvt_pk_f32_fp8((int)u.x, true) * w;
  acc[2] += __builtin_amdgcn_cvt_pk_f32_fp8((int)u.y, false) * w;
  acc[3] += __builtin_amdgcn_cvt_pk_f32_fp8((int)u.y, true) * w;
  acc[4] += __builtin_amdgcn_cvt_pk_f32_fp8((int)u.z, false) * w;
  acc[5] += __builtin_amdgcn_cvt_pk_f32_fp8((int)u.z, true) * w;
  acc[6] += __builtin_amdgcn_cvt_pk_f32_fp8((int)u.w, false) * w;
  acc[7] += __builtin_amdgcn_cvt_pk_f32_fp8((int)u.w, true) * w;
}

// Fused per-anchor sampler. grid 4096 x 256.
__global__ __launch_bounds__(256, 8) void k_sample(
    const float* __restrict__ anchor, const unsigned short* __restrict__ logitsP,
    const float* __restrict__ learn_g, const unsigned char* __restrict__ featF,
    const float* __restrict__ proj, const float* __restrict__ wh,
    unsigned short* __restrict__ featsB) {
  const int n = blockIdx.x;
  const int tid = threadIdx.x;
  const int lane = tid & 63;
  const int wave = tid >> 6;
  __shared__ __align__(16) unsigned short s_w[8 * 328];  // bf16 weights [g][t]
  __shared__ float s_p2d[78][2];
  __shared__ float s_learn[18];
  __shared__ union SmpLds {
    struct { int4 off[320]; float4 wt[320]; } tab;  // 10240 B
    float red[4][256];                              //  4096 B
  } u;

  // phase 1: pre-permuted logits row -> LDS (pure linear uint4 copy).
  {
    const uint4* lp = (const uint4*)(logitsP + (size_t)n * 2496);
    for (int i = tid; i < 312; i += 256) {
      const int g = i / 39;
      ((uint4*)s_w)[g * 41 + (i - g * 39)] = lp[i];
    }
  }
  if (tid < 64) s_w[(tid >> 3) * 328 + 312 + (tid & 7)] = 0;  // zero pad tasks
  if (tid < 18) s_learn[tid] = learn_g[n * 18 + tid];
  __syncthreads();

  // phase 2: softmax over the 312 tasks per group; wave w -> groups 2w, 2w+1
#pragma unroll
  for (int gg = 0; gg < 2; ++gg) {
    unsigned short* row = &s_w[(wave * 2 + gg) * 328];
    float l[5];
    float mx = -1e30f;
#pragma unroll
    for (int i = 0; i < 5; ++i) {
      const int s = lane + i * 64;
      l[i] = (s < 312) ? bf2f(row[s]) : -1e30f;
      mx = fmaxf(mx, l[i]);
    }
    for (int off = 32; off; off >>= 1) mx = fmaxf(mx, __shfl_xor(mx, off));
    float sum = 0.f;
#pragma unroll
    for (int i = 0; i < 5; ++i) {
      l[i] = __expf(l[i] - mx);
      sum += l[i];
    }
    for (int off = 32; off; off >>= 1) sum += __shfl_xor(sum, off);
    const float inv = 1.f / sum;
#pragma unroll
    for (int i = 0; i < 5; ++i) {
      const int s = lane + i * 64;
      if (s < 312) row[s] = (unsigned short)f2bf(l[i] * inv);
    }
  }

  // phase 3: projection of 78 (pt,cam) pairs
  if (tid < 78) {
    const int p = tid / 6, c = tid % 6;
    const float* an = anchor + n * 11;
    float qw = an[6], qx = an[7], qy = an[8], qz = an[9];
    const float qinv = 1.f / sqrtf(qw * qw + qx * qx + qy * qy + qz * qz);
    qw *= qinv; qx *= qinv; qy *= qinv; qz *= qinv;
    const float R00 = 1.f - 2.f * (qy * qy + qz * qz), R01 = 2.f * (qx * qy - qw * qz), R02 = 2.f * (qx * qz + qw * qy);
    const float R10 = 2.f * (qx * qy + qw * qz), R11 = 1.f - 2.f * (qx * qx + qz * qz), R12 = 2.f * (qy * qz - qw * qx);
    const float R20 = 2.f * (qx * qz - qw * qy), R21 = 2.f * (qy * qz + qw * qx), R22 = 1.f - 2.f * (qx * qx + qy * qy);
    float s0, s1, s2;
    if (p < 7) {
      s0 = FIXS[p][0]; s1 = FIXS[p][1]; s2 = FIXS[p][2];
    } else {
      const int b = (p - 7) * 3;
      s0 = s_learn[b]; s1 = s_learn[b + 1]; s2 = s_learn[b + 2];
    }
    const float vx = s0 * an[3], vy = s1 * an[4], vz = s2 * an[5];
    const float kx = R00 * vx + R10 * vy + R20 * vz + an[0];
    const float ky = R01 * vx + R11 * vy + R21 * vz + an[1];
    const float kz = R02 * vx + R12 * vy + R22 * vz + an[2];
    const float* P = proj + c * 16;
    const float h0 = P[0] * kx + P[1] * ky + P[2] * kz + P[3];
    const float h1 = P[4] * kx + P[5] * ky + P[6] * kz + P[7];
    const float h2 = P[8] * kx + P[9] * ky + P[10] * kz + P[11];
    const float zz = fmaxf(h2, 1e-5f);
    float px = h0 / zz / wh[c * 2 + 0];
    float py = h1 / zz / wh[c * 2 + 1];
    px = fminf(fmaxf(px, 0.f), 0.9999f);
    py = fminf(fmaxf(py, 0.f), 0.9999f);
    s_p2d[tid][0] = px;
    s_p2d[tid][1] = py;
  }
  __syncthreads();

  // phase 4: per-task corner BYTE offsets + bilinear weights; pad tasks zeroed
  {
    constexpr int LBB[4] = {FT_L0, FT_L1, FT_L2, FT_L3};
    constexpr int CSB[4] = {2883584, 720896, 180224, 45056};  // H*W*256
    for (int t = tid; t < 320; t += 256) {
      const int pc = t >> 2, l = t & 3;
      if (pc >= 78) {
        u.tab.off[t] = make_int4(0, 0, 0, 0);
        u.tab.wt[t] = make_float4(0.f, 0.f, 0.f, 0.f);
        continue;
      }
      const int c = pc % 6;
      const int H = 64 >> l, W = 176 >> l;
      const float fx = s_p2d[pc][0] * (float)W - 0.5f;
      const float fy = s_p2d[pc][1] * (float)H - 0.5f;
      const float x0f = floorf(fx), y0f = floorf(fy);
      const float wx = fx - x0f, wy = fy - y0f;
      const int x0 = (int)x0f, y0 = (int)y0f;
      const float mx0 = (x0 >= 0) ? 1.f : 0.f;
      const float mx1 = (x0 + 1 < W) ? 1.f : 0.f;
      const float my0 = (y0 >= 0) ? 1.f : 0.f;
      const float my1 = (y0 + 1 < H) ? 1.f : 0.f;
      const int cx0 = max(x0, 0), cx1 = min(x0 + 1, W - 1);
      const int cy0 = max(y0, 0), cy1 = min(y0 + 1, H - 1);
      const int base = LBB[l] + c * CSB[l];
      int4 o;
      o.x = base + (cy0 * W + cx0) * 256;
      o.y = base + (cy0 * W + cx1) * 256;
      o.z = base + (cy1 * W + cx0) * 256;
      o.w = base + (cy1 * W + cx1) * 256;
      u.tab.off[t] = o;
      float4 w4;
      w4.x = (1.f - wx) * (1.f - wy) * mx0 * my0;
      w4.y = wx * (1.f - wy) * mx1 * my0;
      w4.z = (1.f - wx) * wy * mx0 * my1;
      w4.w = wx * wy * mx1 * my1;
      u.tab.wt[t] = w4;
    }
  }
  __syncthreads();

  // phase 5: fp8 gather. quarter-wave = one pc; 16 fp8 channels per lane.
  const int q = lane >> 4;
  const int ql = lane & 15;
  const int chb = ql * 16;
  const int g = ql >> 1;
  v2f acc[8];
#pragma unroll
  for (int k = 0; k < 8; ++k) acc[k] = (v2f){0.f, 0.f};
  const unsigned char* fbl = featF + chb;  // per-lane pre-offset base
  const unsigned short* wrow = &s_w[g * 328];
  const int pcb = wave * 4 + q;
#pragma unroll
  for (int it = 0; it < 5; ++it) {
    const int pc = pcb + it * 16;   // < 80 (tasks >= 312 are zero-weighted)
    const int t0 = pc * 4;
    const uint2 wq = *(const uint2*)&wrow[t0];  // 4 bf16 level-weights
    float wgl[4];
    wgl[0] = __uint_as_float(wq.x << 16);
    wgl[1] = __uint_as_float(wq.x & 0xffff0000u);
    wgl[2] = __uint_as_float(wq.y << 16);
    wgl[3] = __uint_as_float(wq.y & 0xffff0000u);
#pragma unroll
    for (int l4 = 0; l4 < 4; ++l4) {
      const int t = t0 + l4;
      const int4 o = u.tab.off[t];
      const float4 bw = u.tab.wt[t];
      const float wg = wgl[l4];
      const uint4 u0 = *(const uint4*)(fbl + o.x);
      const uint4 u1 = *(const uint4*)(fbl + o.y);
      const uint4 u2 = *(const uint4*)(fbl + o.z);
      const uint4 u3 = *(const uint4*)(fbl + o.w);
      fma16(u0, bw.x * wg, acc);
      fma16(u1, bw.y * wg, acc);
      fma16(u2, bw.z * wg, acc);
      fma16(u3, bw.w * wg, acc);
    }
  }
#pragma unroll
  for (int k = 0; k < 8; ++k) {
    v2f b;
    b.x = __shfl_xor(acc[k].x, 16);
    b.y = __shfl_xor(acc[k].y, 16);
    acc[k] += b;
    b.x = __shfl_xor(acc[k].x, 32);
    b.y = __shfl_xor(acc[k].y, 32);
    acc[k] += b;
  }
  __syncthreads();  // u.tab reads done in ALL waves before u.red is written
  if (lane < 16) {
    float* dst = &u.red[wave][ql * 16];
    *(float4*)(dst + 0)  = make_float4(acc[0].x, acc[0].y, acc[1].x, acc[1].y);
    *(float4*)(dst + 4)  = make_float4(acc[2].x, acc[2].y, acc[3].x, acc[3].y);
    *(float4*)(dst + 8)  = make_float4(acc[4].x, acc[4].y, acc[5].x, acc[5].y);
    *(float4*)(dst + 12) = make_float4(acc[6].x, acc[6].y, acc[7].x, acc[7].y);
  }
  __syncthreads();
  {
    const float sum = u.red[0][tid] + u.red[1][tid] + u.red[2][tid] + u.red[3][tid];
    featsB[n * 256 + tid] = (unsigned short)f2bf(sum);
  }
}

// MFMA GEMM: out = featsB(4096x256) @ Wob^T + b_out + resid. grid (4,64)
__global__ __launch_bounds__(256) void k_out_mfma(
    const unsigned short* __restrict__ Ab, const unsigned short* __restrict__ Bb,
    const float* __restrict__ bias, const float* __restrict__ resid,
    float* __restrict__ out) {
  const int tid = threadIdx.x;
  const int w = tid >> 6, lane = tid & 63;
  const int ml = lane & 15, q = lane >> 4;
  const int n0 = blockIdx.x * 64;
  const int m0 = blockIdx.y * 64;
  f32x4 acc[4] = {{0.f, 0.f, 0.f, 0.f}, {0.f, 0.f, 0.f, 0.f},
                  {0.f, 0.f, 0.f, 0.f}, {0.f, 0.f, 0.f, 0.f}};
  const unsigned short* Ap = Ab + (m0 + w * 16 + ml) * 256 + q * 8;
  const unsigned short* Bp = Bb + (n0 + ml) * 256 + q * 8;
#pragma unroll
  for (int kk = 0; kk < 8; ++kk) {
    const bf16x8 a = *(const bf16x8*)(Ap + kk * 32);
#pragma unroll
    for (int nt = 0; nt < 4; ++nt) {
      const bf16x8 b = *(const bf16x8*)(Bp + nt * 16 * 256 + kk * 32);
      acc[nt] = __builtin_amdgcn_mfma_f32_16x16x32_bf16(a, b, acc[nt], 0, 0, 0);
    }
  }
  const int rowb = m0 + w * 16 + q * 4;
#pragma unroll
  for (int nt = 0; nt < 4; ++nt) {
    const int col = n0 + nt * 16 + ml;
    const float b = bias[col];
#pragma unroll
    for (int r = 0; r < 4; ++r) {
      const int row = rowb + r;
      out[row * 256 + col] = acc[nt][r] + b + resid[row * 256 + col];
    }
  }
}

extern "C" void kernel_launch(void* const* d_in, const int* in_sizes, int n_in,
                              void* d_out, int out_size, void* d_ws, size_t ws_size,
                              hipStream_t stream) {
  (void)in_sizes; (void)n_in; (void)out_size; (void)ws_size;
  const float* iw      = (const float*)d_in[1];
  const float* anchor  = (const float*)d_in[2];
  const float* f0      = (const float*)d_in[3];
  const float* f1      = (const float*)d_in[4];
  const float* f2      = (const float*)d_in[5];
  const float* f3      = (const float*)d_in[6];
  const float* proj    = (const float*)d_in[7];
  const float* wh      = (const float*)d_in[8];
  const float* W_learn = (const float*)d_in[9];
  const float* b_learn = (const float*)d_in[10];
  const float* W_wts   = (const float*)d_in[11];
  const float* b_wts   = (const float*)d_in[12];
  const float* W_out   = (const float*)d_in[13];
  const float* b_out   = (const float*)d_in[14];
  float* out = (float*)d_out;
  float* ws = (float*)d_ws;
  unsigned char*  featF   = (unsigned char*)ws;
  unsigned short* logitsP = (unsigned short*)(ws + WS_LOGB);
  unsigned short* featsB  = (unsigned short*)(ws + WS_FEATB);
  float*          learn   = ws + WS_LEARN;
  unsigned short* Ab      = (unsigned short*)(ws + WS_AB);
  unsigned short* Bb      = (unsigned short*)(ws + WS_BB);
  unsigned short* Wob     = (unsigned short*)(ws + WS_WOB);
  float*          biasP   = ws + WS_BIASP;

  k_stage<<<4427, 256, 0, stream>>>(f0, f1, f2, f3, featF, iw, W_wts, W_learn,
                                    W_out, b_wts, Ab, Bb, Wob, biasP);
  k_wts_mfma<<<dim3(40, 64), 256, 0, stream>>>(Ab, Bb, biasP, b_learn, logitsP, learn);
  k_sample<<<4096, 256, 0, stream>>>(anchor, logitsP, learn, featF, proj, wh, featsB);
  k_out_mfma<<<dim3(4, 64), 256, 0, stream>>>(featsB, Wob, b_out, iw, out);
}